// Round 4
// baseline (73.559 us; speedup 1.0000x reference)
//
#include <hip/hip_runtime.h>

// Polyphase resample up=3 down=2, N=2097152, L=129 taps, start=(L-1)/2=64.
// out[3j+0] = 3 * sum_i x[21+2j-i] * h[1+3i]   (i in [0,43))
// out[3j+1] = 3 * sum_i x[22+2j-i] * h[0+3i]
// out[3j+2] = 3 * sum_i x[22+2j-i] * h[2+3i]
// (formula verified: R1-R3 passed, absmax 0.25)
//
// R3 post-mortem: kernel ~28us inferred, latency-stall signature (R2: all
// pipes <12% busy). This round: G=2 (2048 blocks -> 8 blocks/CU, 2x waves),
// explicit 2-deep software pipeline of 11-float LDS windows with
// COMPILE-TIME chunk bases (immediate ds offsets, mergeable ds_read2, h as
// merged s_load prefetch), pad-1-per-4 LDS (lane stride 5 -> conflict-free).

#define N_SIG   2097152
#define L_FILT  129
#define NTAPS   43
#define G       2                            // 2 groups = 6 outputs/thread
#define BLK     256
#define GROUPS_PER_BLK (BLK * G)             // 512 groups -> 1536 outputs/block
#define TILE_Q  1072                         // logical words, covers q in [3,1069)
#define TILE_P  (TILE_Q + TILE_Q / 4)        // 1340: 1 pad word per 4 -> stride 5

// Window for a chunk of U taps starting at compile-time tap I0:
// wz[k] = w[D+k], D = 46-U-I0, size U+2G-1 = U+3.
// Thread's logical tile word for w[d] is Q = 4*tid + d; padded addr
// p = Q + (Q>>2) = 5*tid + D + (D>>2) + k + ((R+k)>>2), R = D&3 (const).
template <int U, int I0>
__device__ __forceinline__ void load_win(const float* __restrict__ xs,
                                         int tid, float (&wz)[U + 3]) {
    constexpr int D = 46 - U - I0;
    constexpr int R = D & 3;
    const int pb = 5 * tid + D + (D >> 2);
#pragma unroll
    for (int k = 0; k < U + 3; ++k)
        wz[k] = xs[pb + k + ((R + k) >> 2)];
}

// xa(u,g) = wz[U-1-u+2g], xb = wz[U-u+2g]; h indices compile-time ->
// wave-uniform merged s_loads.
template <int U, int I0>
__device__ __forceinline__ void fmas(const float* __restrict__ h,
                                     const float (&wz)[U + 3], float (&acc)[3 * G]) {
#pragma unroll
    for (int u = 0; u < U; ++u) {
        const float h0 = h[3 * (I0 + u) + 0];
        const float h1 = h[3 * (I0 + u) + 1];
        const float h2 = h[3 * (I0 + u) + 2];
#pragma unroll
        for (int g = 0; g < G; ++g) {
            const float xa = wz[U - 1 - u + 2 * g];
            const float xb = wz[U - u + 2 * g];
            acc[3 * g + 0] += xa * h1;
            acc[3 * g + 1] += xb * h0;
            acc[3 * g + 2] += xb * h2;
        }
    }
}

__global__ __launch_bounds__(BLK, 4) void poly_kernel(
    const float* __restrict__ x, const float* __restrict__ h,
    float* __restrict__ out, int n_out)
{
    __shared__ float xs[TILE_P];

    const int tid = threadIdx.x;
    const int b   = blockIdx.x;

    // tb = 1024*b - 24: group j = 512b+jl uses x[tb + 45+2jl-i], jl = 2tid+g.
    const int tb = 2 * GROUPS_PER_BLK * b - 24;

    // Coalesced staging with zero-pad at edges. Logical word q at
    // p = q + (q>>2); float4 at q%4==0 -> p = 5*(q/4), never straddles pad.
    for (int q4 = tid; q4 < TILE_Q / 4; q4 += BLK) {
        const int gx = tb + 4 * q4;
        float4 v;
        if (gx >= 0 && gx + 3 < N_SIG) {
            v = *(const float4*)(x + gx);
        } else {
            v.x = (gx     >= 0 && gx     < N_SIG) ? x[gx]     : 0.0f;
            v.y = (gx + 1 >= 0 && gx + 1 < N_SIG) ? x[gx + 1] : 0.0f;
            v.z = (gx + 2 >= 0 && gx + 2 < N_SIG) ? x[gx + 2] : 0.0f;
            v.w = (gx + 3 >= 0 && gx + 3 < N_SIG) ? x[gx + 3] : 0.0f;
        }
        const int p = 5 * q4;
        xs[p + 0] = v.x; xs[p + 1] = v.y; xs[p + 2] = v.z; xs[p + 3] = v.w;
    }
    __syncthreads();

    float acc[3 * G];
#pragma unroll
    for (int k = 0; k < 3 * G; ++k) acc[k] = 0.0f;

    // Software-pipelined chunks: load window c+1 before FMAs of chunk c.
    // Live window regs <= 11+11+6; VGPR bounded, no spill (launch_bounds 128).
    float w0[11], w1[11], wt[6];
    load_win<8, 0 >(xs, tid, w0);
    load_win<8, 8 >(xs, tid, w1);
    fmas<8, 0 >(h, w0, acc);
    load_win<8, 16>(xs, tid, w0);
    fmas<8, 8 >(h, w1, acc);
    load_win<8, 24>(xs, tid, w1);
    fmas<8, 16>(h, w0, acc);
    load_win<8, 32>(xs, tid, w0);
    fmas<8, 24>(h, w1, acc);
    load_win<3, 40>(xs, tid, wt);
    fmas<8, 32>(h, w0, acc);
    fmas<3, 40>(h, wt, acc);

    // 6 outputs/thread at ob = 1536b + 6tid (8B-aligned); fold gain 3 here.
    const int ob = 3 * GROUPS_PER_BLK * b + 3 * G * tid;
#pragma unroll
    for (int k = 0; k < 3; ++k) {
        if (ob + 2 * k + 1 < n_out) {
            *(float2*)(out + ob + 2 * k) =
                make_float2(3.0f * acc[2 * k], 3.0f * acc[2 * k + 1]);
        }
    }
}

extern "C" void kernel_launch(void* const* d_in, const int* in_sizes, int n_in,
                              void* d_out, int out_size, void* d_ws, size_t ws_size,
                              hipStream_t stream) {
    const float* x = (const float*)d_in[0];
    const float* h = (const float*)d_in[1];
    float* out = (float*)d_out;
    const int blocks = (out_size + 3 * GROUPS_PER_BLK - 1) / (3 * GROUPS_PER_BLK);
    poly_kernel<<<blocks, BLK, 0, stream>>>(x, h, out, out_size);
}